// Round 5
// baseline (390.146 us; speedup 1.0000x reference)
//
#include <hip/hip_runtime.h>
#include <math.h>

#define NE  8
#define D   2048
#define TPB 256

// Fold 8 accumulators across an 8-lane butterfly: returns expert (lane&7)'s
// sum over the lane's 8-lane group. 7 shuffles instead of 24.
__device__ __forceinline__ float fold8(const float* acc, int lane) {
  float r_[4];
  const bool s1 = lane & 1;
#pragma unroll
  for (int k = 0; k < 4; ++k) {
    float send = s1 ? acc[2*k] : acc[2*k+1];
    float recv = __shfl_xor(send, 1, 64);
    r_[k] = (s1 ? acc[2*k+1] : acc[2*k]) + recv;
  }
  const bool s2 = lane & 2;
  float q[2];
#pragma unroll
  for (int k = 0; k < 2; ++k) {
    float send = s2 ? r_[2*k] : r_[2*k+1];
    float recv = __shfl_xor(send, 2, 64);
    q[k] = (s2 ? r_[2*k+1] : r_[2*k]) + recv;
  }
  const bool s4 = lane & 4;
  float send = s4 ? q[0] : q[1];
  float recv = __shfl_xor(send, 4, 64);
  return (s4 ? q[1] : q[0]) + recv;
}

__global__ __launch_bounds__(TPB, 3) void router_main(
    const float* __restrict__ x, const float* __restrict__ Wg,
    float* __restrict__ outW, float* __restrict__ outI,
    float* __restrict__ ws, int N, int G)
{
  __shared__ float part[2][64];   // double-buffered: 2 rows x 4 waves x 8 experts
  const int t    = threadIdx.x;
  const int lane = t & 63;
  const int wvid = t >> 6;

  // W_gate registers: thread t owns d-elements [8t, 8t+8); w[j*8+e]
  float w[64];
  {
    const float4* wg4 = (const float4*)Wg + t * 16;
#pragma unroll
    for (int k = 0; k < 16; ++k) {
      float4 v = wg4[k];
      w[4*k+0] = v.x; w[4*k+1] = v.y; w[4*k+2] = v.z; w[4*k+3] = v.w;
    }
  }

  float impAcc = 0.f, cntAcc = 0.f;

  const int step = 2 * G;
  int r0 = blockIdx.x;
  float4 a0 = make_float4(0.f,0.f,0.f,0.f), b0 = a0, a1 = a0, b1 = a0;
  if (r0 < N)     { const float4* p = (const float4*)(x + (size_t)r0      * D) + t*2; a0 = p[0]; b0 = p[1]; }
  if (r0 + G < N) { const float4* p = (const float4*)(x + (size_t)(r0+G)  * D) + t*2; a1 = p[0]; b1 = p[1]; }

  int buf = 0;
  for (; r0 < N; r0 += step) {
    const int r1 = r0 + G;
    // prefetch next pair
    const int n0 = r0 + step, n1 = r1 + step;
    float4 pa0 = make_float4(0.f,0.f,0.f,0.f), pb0 = pa0, pa1 = pa0, pb1 = pa0;
    if (n0 < N) { const float4* p = (const float4*)(x + (size_t)n0 * D) + t*2; pa0 = p[0]; pb0 = p[1]; }
    if (n1 < N) { const float4* p = (const float4*)(x + (size_t)n1 * D) + t*2; pa1 = p[0]; pb1 = p[1]; }

    float xv0[8] = {a0.x,a0.y,a0.z,a0.w,b0.x,b0.y,b0.z,b0.w};
    float xv1[8] = {a1.x,a1.y,a1.z,a1.w,b1.x,b1.y,b1.z,b1.w};
    float acc0[NE], acc1[NE];
#pragma unroll
    for (int e = 0; e < NE; ++e) { acc0[e] = 0.f; acc1[e] = 0.f; }
#pragma unroll
    for (int j = 0; j < 8; ++j)
#pragma unroll
      for (int e = 0; e < NE; ++e) {
        acc0[e] = fmaf(xv0[j], w[j*8+e], acc0[e]);
        acc1[e] = fmaf(xv1[j], w[j*8+e], acc1[e]);
      }

    // 8-lane-group fold, then cross-group reduce (both rows interleaved)
    float v0 = fold8(acc0, lane);
    float v1 = fold8(acc1, lane);
#pragma unroll
    for (int m = 8; m <= 32; m <<= 1) {
      v0 += __shfl_xor(v0, m, 64);
      v1 += __shfl_xor(v1, m, 64);
    }

    if (lane < 8) {
      part[buf][     wvid*8 + lane] = v0;   // lane == expert id
      part[buf][32 + wvid*8 + lane] = v1;
    }
    __syncthreads();   // single barrier per 2 rows (part is double-buffered)

    if (t < NE) {
      float h0[NE], h1[NE];
#pragma unroll
      for (int e = 0; e < NE; ++e) {
        h0[e] = part[buf][e]    + part[buf][8+e]  + part[buf][16+e] + part[buf][24+e];
        h1[e] = part[buf][32+e] + part[buf][40+e] + part[buf][48+e] + part[buf][56+e];
      }

      // ---- row r0 ----
      {
        int i1 = 0; float m1 = h0[0];
#pragma unroll
        for (int e = 1; e < NE; ++e) if (h0[e] > m1) { m1 = h0[e]; i1 = e; }
        int i2 = -1; float m2 = -INFINITY;
#pragma unroll
        for (int e = 0; e < NE; ++e) if (e != i1 && h0[e] > m2) { m2 = h0[e]; i2 = e; }
        if (t == 0) {
          float e2 = __expf(m2 - m1);
          float dd = __fdividef(1.f, 1.f + e2);
          *(float2*)(outW + (size_t)r0*2) = make_float2(dd, e2 * dd);
          *(float2*)(outI + (size_t)r0*2) = make_float2((float)i1, (float)i2);
        }
        float s = 0.f;
#pragma unroll
        for (int e = 0; e < NE; ++e) s += __expf(h0[e] - m1);
        impAcc += __fdividef(__expf(h0[t] - m1), s);
        cntAcc += (float)((t == i1) + (t == i2));
      }
      // ---- row r1 ----
      if (r1 < N) {
        int i1 = 0; float m1 = h1[0];
#pragma unroll
        for (int e = 1; e < NE; ++e) if (h1[e] > m1) { m1 = h1[e]; i1 = e; }
        int i2 = -1; float m2 = -INFINITY;
#pragma unroll
        for (int e = 0; e < NE; ++e) if (e != i1 && h1[e] > m2) { m2 = h1[e]; i2 = e; }
        if (t == 1) {
          float e2 = __expf(m2 - m1);
          float dd = __fdividef(1.f, 1.f + e2);
          *(float2*)(outW + (size_t)r1*2) = make_float2(dd, e2 * dd);
          *(float2*)(outI + (size_t)r1*2) = make_float2((float)i1, (float)i2);
        }
        float s = 0.f;
#pragma unroll
        for (int e = 0; e < NE; ++e) s += __expf(h1[e] - m1);
        impAcc += __fdividef(__expf(h1[t] - m1), s);
        cntAcc += (float)((t == i1) + (t == i2));
      }
    }
    buf ^= 1;
    a0 = pa0; b0 = pb0; a1 = pa1; b1 = pb1;
  }

  if (t < NE) {
    atomicAdd(&ws[t],      impAcc);   // importance[e]
    atomicAdd(&ws[NE + t], cntAcc);   // load[e]
  }
}

__global__ void router_final(const float* __restrict__ ws, float* __restrict__ out)
{
  if (threadIdx.x == 0 && blockIdx.x == 0) {
    float mi = 0.f, ml = 0.f;
    for (int e = 0; e < NE; ++e) { mi += ws[e]; ml += ws[NE + e]; }
    mi *= (1.f / NE); ml *= (1.f / NE);
    float vi = 0.f, vl = 0.f;
    for (int e = 0; e < NE; ++e) {
      float di = ws[e] - mi, dl = ws[NE + e] - ml;
      vi += di * di; vl += dl * dl;
    }
    float si = sqrtf(vi / (NE - 1));   // ddof=1
    float sl = sqrtf(vl / (NE - 1));
    float cv = sl / (ml + 1e-6f) + si / (mi + 1e-6f);
    out[0] = cv * 0.01f;
  }
}

extern "C" void kernel_launch(void* const* d_in, const int* in_sizes, int n_in,
                              void* d_out, int out_size, void* d_ws, size_t ws_size,
                              hipStream_t stream) {
  const float* x  = (const float*)d_in[0];
  const float* Wg = (const float*)d_in[1];
  // d_in[2] = W_noise (unused in eval), d_in[3] = top_k (fixed at 2)

  const int N = in_sizes[0] / D;          // 32768 rows
  float* out  = (float*)d_out;
  float* outW = out;                       // [N,2] dispatch weights
  float* outI = out + (size_t)N * 2;       // [N,2] indices as float
  float* aux  = out + (size_t)N * 4;       // scalar aux loss
  float* ws   = (float*)d_ws;              // [0..7]=importance, [8..15]=load

  hipMemsetAsync(d_ws, 0, 16 * sizeof(float), stream);

  int grid = 2048;
  if (grid > N) grid = N;
  router_main<<<grid, TPB, 0, stream>>>(x, Wg, outW, outI, ws, N, grid);
  router_final<<<1, 64, 0, stream>>>(ws, aux);
}